// Round 2
// baseline (251.006 us; speedup 1.0000x reference)
//
#include <hip/hip_runtime.h>
#include <hip/hip_bf16.h>
#include <cstdint>

#define DIMD 1024
#define NH 16
#define DHD 64
#define BB 2
#define TT 2048
#define MROWS (BB * TT)   // 4096

typedef unsigned short u16;
typedef __attribute__((ext_vector_type(8))) __bf16 bf16x8;
typedef __attribute__((ext_vector_type(4))) float f32x4;

__device__ __forceinline__ float bf2f(u16 u) {
    union { unsigned int i; float f; } v; v.i = ((unsigned int)u) << 16; return v.f;
}
__device__ __forceinline__ u16 f2bf(float f) {
    union { float f; unsigned int i; } v; v.f = f;
    unsigned int u = v.i;
    unsigned int r = (u + 0x7fffu + ((u >> 16) & 1u)) >> 16;
    return (u16)r;
}
__device__ __forceinline__ int4 pack8(const float4& a, const float4& b) {
    union { int4 v; u16 u[8]; } t;
    t.u[0] = f2bf(a.x); t.u[1] = f2bf(a.y); t.u[2] = f2bf(a.z); t.u[3] = f2bf(a.w);
    t.u[4] = f2bf(b.x); t.u[5] = f2bf(b.y); t.u[6] = f2bf(b.z); t.u[7] = f2bf(b.w);
    return t.v;
}

// ---------------------------------------------------------------------------
// C[m,n] = sum_k A[m,k] * W[n,k].  A: MROWSxKd (f32 or bf16 per AF32),
// W: NdxKd f32, C: MROWSxNd (f32 or bf16 per CF32). Compute in bf16 MFMA,
// f32 accumulate. 128x128 tile, 256 threads = 4 waves (2x2), each wave 64x64
// via 4x4 grid of 16x16x32 bf16 MFMA.
// ---------------------------------------------------------------------------
template <bool AF32, bool CF32>
__global__ __launch_bounds__(256) void gemm_bt(const void* __restrict__ Ap,
                                               const float* __restrict__ W,
                                               void* __restrict__ Cp) {
    constexpr int Kd = 1024, Nd = 1024;
    constexpr int LDA = 40;                  // 32 + 8 pad (16B aligned rows)
    __shared__ u16 As[128 * LDA];
    __shared__ u16 Bs[128 * LDA];

    const int tid = threadIdx.x;
    const int L   = tid & 63;
    const int w   = tid >> 6;
    const int wm  = (w >> 1) * 64;
    const int wn  = (w & 1) * 64;
    const int m0  = blockIdx.y * 128;
    const int n0  = blockIdx.x * 128;

    const int srow = tid >> 2;               // 0..63
    const int skc  = (tid & 3) * 8;          // 0,8,16,24 (elements)
    const float* Wg  = W + (size_t)(n0 + srow) * Kd + skc;
    const float* Agf = (const float*)Ap + (size_t)(m0 + srow) * Kd + skc;
    const u16*   Agh = (const u16*)Ap + (size_t)(m0 + srow) * Kd + skc;
    u16* Asw = &As[srow * LDA + skc];
    u16* Bsw = &Bs[srow * LDA + skc];

    const int r16 = L & 15;
    const int q8  = (L >> 4) * 8;

    f32x4 acc[4][4];
#pragma unroll
    for (int i = 0; i < 4; i++)
#pragma unroll
        for (int j = 0; j < 4; j++) acc[i][j] = f32x4{0.f, 0.f, 0.f, 0.f};

    // prefetch k0 = 0
    float4 wa0 = *(const float4*)(Wg);
    float4 wb0 = *(const float4*)(Wg + 4);
    float4 wa1 = *(const float4*)(Wg + 64 * Kd);
    float4 wb1 = *(const float4*)(Wg + 64 * Kd + 4);
    float4 aa0, ab0, aa1, ab1;
    int4 ah0, ah1;
    if constexpr (AF32) {
        aa0 = *(const float4*)(Agf);
        ab0 = *(const float4*)(Agf + 4);
        aa1 = *(const float4*)(Agf + 64 * Kd);
        ab1 = *(const float4*)(Agf + 64 * Kd + 4);
    } else {
        ah0 = *(const int4*)(Agh);
        ah1 = *(const int4*)(Agh + 64 * Kd);
    }

    for (int k0 = 0; k0 < Kd; k0 += 32) {
        __syncthreads();
        if constexpr (AF32) {
            *(int4*)(Asw)            = pack8(aa0, ab0);
            *(int4*)(Asw + 64 * LDA) = pack8(aa1, ab1);
        } else {
            *(int4*)(Asw)            = ah0;
            *(int4*)(Asw + 64 * LDA) = ah1;
        }
        *(int4*)(Bsw)            = pack8(wa0, wb0);
        *(int4*)(Bsw + 64 * LDA) = pack8(wa1, wb1);
        __syncthreads();

        if (k0 + 32 < Kd) {                  // prefetch next tile
            int kn = k0 + 32;
            wa0 = *(const float4*)(Wg + kn);
            wb0 = *(const float4*)(Wg + kn + 4);
            wa1 = *(const float4*)(Wg + 64 * Kd + kn);
            wb1 = *(const float4*)(Wg + 64 * Kd + kn + 4);
            if constexpr (AF32) {
                aa0 = *(const float4*)(Agf + kn);
                ab0 = *(const float4*)(Agf + kn + 4);
                aa1 = *(const float4*)(Agf + 64 * Kd + kn);
                ab1 = *(const float4*)(Agf + 64 * Kd + kn + 4);
            } else {
                ah0 = *(const int4*)(Agh + kn);
                ah1 = *(const int4*)(Agh + 64 * Kd + kn);
            }
        }

        bf16x8 af[4], bfr[4];
#pragma unroll
        for (int i = 0; i < 4; i++)
            af[i] = *(const bf16x8*)&As[(wm + i * 16 + r16) * LDA + q8];
#pragma unroll
        for (int i = 0; i < 4; i++)
            bfr[i] = *(const bf16x8*)&Bs[(wn + i * 16 + r16) * LDA + q8];
#pragma unroll
        for (int mi = 0; mi < 4; mi++)
#pragma unroll
            for (int ni = 0; ni < 4; ni++)
                acc[mi][ni] = __builtin_amdgcn_mfma_f32_16x16x32_bf16(
                    af[mi], bfr[ni], acc[mi][ni], 0, 0, 0);
    }

    // epilogue: C/D layout row=(lane>>4)*4+r, col=lane&15
#pragma unroll
    for (int mi = 0; mi < 4; mi++)
#pragma unroll
        for (int ni = 0; ni < 4; ni++)
#pragma unroll
            for (int r = 0; r < 4; r++) {
                int row = m0 + wm + mi * 16 + (L >> 4) * 4 + r;
                int col = n0 + wn + ni * 16 + r16;
                if constexpr (CF32)
                    ((float*)Cp)[(size_t)row * Nd + col] = acc[mi][ni][r];
                else
                    ((u16*)Cp)[(size_t)row * Nd + col] = f2bf(acc[mi][ni][r]);
            }
}

// ---------------------------------------------------------------------------
// In-place RoPE on q and k (bf16, (B,T,H,DH) layout). rot is f32 (B,T,DH).
// One thread per (b,t,h,d<32).
// ---------------------------------------------------------------------------
__global__ __launch_bounds__(256) void rope_kernel(u16* __restrict__ q,
                                                   u16* __restrict__ k,
                                                   const float* __restrict__ rot) {
    int idx = blockIdx.x * 256 + threadIdx.x;    // [0, B*T*H*32)
    int d  = idx & 31;
    int h  = (idx >> 5) & (NH - 1);
    int bt = idx >> 9;

    float r1 = rot[bt * DHD + d];
    float r2 = rot[bt * DHD + d + 32];
    float s1, c1, s2, c2;
    __sincosf(r1, &s1, &c1);
    __sincosf(r2, &s2, &c2);

    size_t base = (size_t)bt * DIMD + h * DHD;
    float q1 = bf2f(q[base + d]), q2 = bf2f(q[base + d + 32]);
    q[base + d]      = f2bf(q1 * c1 - q2 * s1);
    q[base + d + 32] = f2bf(q2 * c2 + q1 * s2);
    float k1 = bf2f(k[base + d]), k2 = bf2f(k[base + d + 32]);
    k[base + d]      = f2bf(k1 * c1 - k2 * s1);
    k[base + d + 32] = f2bf(k2 * c2 + k1 * s2);
}

// ---------------------------------------------------------------------------
// Windowed causal attention: keys k in [q-128, q]. Block = (b, h, 64 queries),
// 4 waves, wave w owns 16 queries. Key tile = 192 keys [q0-128, q0+63].
// All operands bf16 in workspace.
// ---------------------------------------------------------------------------
__global__ __launch_bounds__(256) void attn_kernel(const u16* __restrict__ Q,
                                                   const u16* __restrict__ K,
                                                   const u16* __restrict__ V,
                                                   u16* __restrict__ O) {
    constexpr int LDK = 72;    // 64 + 8 pad
    constexpr int LDV = 200;   // 192 + 8 pad
    __shared__ u16 Ks[192 * LDK];      // reused as P (4 waves x 16 x LDV)
    __shared__ u16 Qs[64 * LDK];
    __shared__ u16 VTs[64 * LDV];      // V transposed: [dh][key]

    const int tid = threadIdx.x;
    const int L   = tid & 63;
    const int w   = tid >> 6;
    const int b   = blockIdx.z;
    const int h   = blockIdx.y;
    const int q0  = blockIdx.x * 64;
    const int kstart = q0 - 128;

    // ---- stage Q (64x64), K (192x64), V^T (64x192) ----
    for (int i = tid; i < 512; i += 256) {
        int qr = i >> 3, c = (i & 7) * 8;
        int t = q0 + qr;
        *(int4*)&Qs[qr * LDK + c] =
            *(const int4*)&Q[(size_t)(b * TT + t) * DIMD + h * DHD + c];
    }
    for (int i = tid; i < 1536; i += 256) {
        int kr = i >> 3, c = (i & 7) * 8;
        int kk = kstart + kr;
        int4 val = make_int4(0, 0, 0, 0);
        if (kk >= 0)
            val = *(const int4*)&K[(size_t)(b * TT + kk) * DIMD + h * DHD + c];
        *(int4*)&Ks[kr * LDK + c] = val;
    }
    for (int i = tid; i < 1536; i += 256) {
        int kr = i >> 3, c = (i & 7) * 8;
        int kk = kstart + kr;
        union { int4 v; u16 u[8]; } tmp;
        tmp.v = make_int4(0, 0, 0, 0);
        if (kk >= 0)
            tmp.v = *(const int4*)&V[(size_t)(b * TT + kk) * DIMD + h * DHD + c];
#pragma unroll
        for (int j = 0; j < 8; j++) VTs[(c + j) * LDV + kr] = tmp.u[j];
    }
    __syncthreads();

    const int r16  = L & 15;
    const int quad = L >> 4;
    const int q8   = quad * 8;

    // ---- QK^T: S[16 x 192] per wave ----
    bf16x8 aq0 = *(const bf16x8*)&Qs[(w * 16 + r16) * LDK + q8];
    bf16x8 aq1 = *(const bf16x8*)&Qs[(w * 16 + r16) * LDK + 32 + q8];

    float st[12][4];
    float rmax[4] = {-1e30f, -1e30f, -1e30f, -1e30f};
    const float SC = 0.125f;   // 1/sqrt(64)

#pragma unroll
    for (int kt = 0; kt < 12; kt++) {
        bf16x8 bk0 = *(const bf16x8*)&Ks[(kt * 16 + r16) * LDK + q8];
        bf16x8 bk1 = *(const bf16x8*)&Ks[(kt * 16 + r16) * LDK + 32 + q8];
        f32x4 s = f32x4{0.f, 0.f, 0.f, 0.f};
        s = __builtin_amdgcn_mfma_f32_16x16x32_bf16(aq0, bk0, s, 0, 0, 0);
        s = __builtin_amdgcn_mfma_f32_16x16x32_bf16(aq1, bk1, s, 0, 0, 0);
        int ka = kstart + kt * 16 + r16;
#pragma unroll
        for (int r = 0; r < 4; r++) {
            int qa = q0 + w * 16 + quad * 4 + r;
            float sv = s[r] * SC;
            bool ok = (ka >= 0) && (ka <= qa) && (ka >= qa - 128);
            sv = ok ? sv : -1e30f;
            st[kt][r] = sv;
            rmax[r] = fmaxf(rmax[r], sv);
        }
    }
#pragma unroll
    for (int off = 8; off >= 1; off >>= 1)
#pragma unroll
        for (int r = 0; r < 4; r++)
            rmax[r] = fmaxf(rmax[r], __shfl_xor(rmax[r], off, 64));

    __syncthreads();   // all waves done reading Ks; safe to overwrite as P

    u16* Ps = &Ks[w * 16 * LDV];
    float rsum[4] = {0.f, 0.f, 0.f, 0.f};
#pragma unroll
    for (int kt = 0; kt < 12; kt++)
#pragma unroll
        for (int r = 0; r < 4; r++) {
            float p = __expf(st[kt][r] - rmax[r]);
            rsum[r] += p;
            Ps[(quad * 4 + r) * LDV + kt * 16 + r16] = f2bf(p);
        }
#pragma unroll
    for (int off = 8; off >= 1; off >>= 1)
#pragma unroll
        for (int r = 0; r < 4; r++)
            rsum[r] += __shfl_xor(rsum[r], off, 64);
    float rinv[4];
#pragma unroll
    for (int r = 0; r < 4; r++) rinv[r] = 1.0f / rsum[r];

    __syncthreads();   // P visible

    // ---- PV: O[16 x 64] per wave ----
    bf16x8 pa[6];
#pragma unroll
    for (int kc = 0; kc < 6; kc++)
        pa[kc] = *(const bf16x8*)&Ps[r16 * LDV + kc * 32 + q8];

#pragma unroll
    for (int nt = 0; nt < 4; nt++) {
        f32x4 acc = f32x4{0.f, 0.f, 0.f, 0.f};
#pragma unroll
        for (int kc = 0; kc < 6; kc++) {
            bf16x8 bv = *(const bf16x8*)&VTs[(nt * 16 + r16) * LDV + kc * 32 + q8];
            acc = __builtin_amdgcn_mfma_f32_16x16x32_bf16(pa[kc], bv, acc, 0, 0, 0);
        }
#pragma unroll
        for (int r = 0; r < 4; r++) {
            int qa = q0 + w * 16 + quad * 4 + r;
            O[(size_t)(b * TT + qa) * DIMD + h * DHD + nt * 16 + r16] =
                f2bf(acc[r] * rinv[r]);
        }
    }
}

// ---------------------------------------------------------------------------
extern "C" void kernel_launch(void* const* d_in, const int* in_sizes, int n_in,
                              void* d_out, int out_size, void* d_ws, size_t ws_size,
                              hipStream_t stream) {
    const float* x   = (const float*)d_in[0];   // (B,T,DIM) f32
    // d_in[1] = attention_mask (all ones) -- ignored
    const float* rot = (const float*)d_in[2];   // (B,T,DH) f32
    const float* Wq  = (const float*)d_in[3];   // (DIM,DIM) f32
    const float* Wk  = (const float*)d_in[4];
    const float* Wv  = (const float*)d_in[5];
    const float* Wo  = (const float*)d_in[6];
    float* out = (float*)d_out;                 // (B,T,DIM) f32

    u16* qb = (u16*)d_ws;                       // 4096x1024 bf16
    u16* kb = qb + (size_t)MROWS * DIMD;
    u16* vb = kb + (size_t)MROWS * DIMD;
    u16* ab = vb + (size_t)MROWS * DIMD;        // attention output (bf16)

    dim3 gg(DIMD / 128, MROWS / 128);           // (8, 32)
    gemm_bt<true, false><<<gg, 256, 0, stream>>>(x, Wq, qb);
    gemm_bt<true, false><<<gg, 256, 0, stream>>>(x, Wk, kb);
    gemm_bt<true, false><<<gg, 256, 0, stream>>>(x, Wv, vb);
    rope_kernel<<<(BB * TT * NH * 32) / 256, 256, 0, stream>>>(qb, kb, rot);
    attn_kernel<<<dim3(TT / 64, NH, BB), 256, 0, stream>>>(qb, kb, vb, ab);
    gemm_bt<false, true><<<gg, 256, 0, stream>>>(ab, Wo, out);
}

// Round 3
// 209.881 us; speedup vs baseline: 1.1959x; 1.1959x over previous
//
#include <hip/hip_runtime.h>
#include <hip/hip_bf16.h>
#include <cstdint>

#define DIMD 1024
#define NH 16
#define DHD 64
#define BB 2
#define TT 2048
#define MROWS (BB * TT)   // 4096

typedef unsigned short u16;
typedef __attribute__((ext_vector_type(8))) __bf16 bf16x8;
typedef __attribute__((ext_vector_type(4))) float f32x4;

__device__ __forceinline__ float bf2f(u16 u) {
    union { unsigned int i; float f; } v; v.i = ((unsigned int)u) << 16; return v.f;
}
__device__ __forceinline__ u16 f2bf(float f) {
    union { float f; unsigned int i; } v; v.f = f;
    unsigned int u = v.i;
    unsigned int r = (u + 0x7fffu + ((u >> 16) & 1u)) >> 16;
    return (u16)r;
}
__device__ __forceinline__ int4 pack8(const float4& a, const float4& b) {
    union { int4 v; u16 u[8]; } t;
    t.u[0] = f2bf(a.x); t.u[1] = f2bf(a.y); t.u[2] = f2bf(a.z); t.u[3] = f2bf(a.w);
    t.u[4] = f2bf(b.x); t.u[5] = f2bf(b.y); t.u[6] = f2bf(b.z); t.u[7] = f2bf(b.w);
    return t.v;
}

// ---------------------------------------------------------------------------
// Fused QKV projection + RoPE epilogue.
// C[m,n] = sum_k x[m,k] * W[n,k], N = 3072 (Q|K|V), tile 64x128.
// 256 threads = 4 waves; wave w owns cols (w>>1)*64 + (w&1)*16 + {0,32} tiles
// so the rotary pair (d, d+32) sits in acc[mi][0] / acc[mi][1] of one lane.
// Grid (24, 64) = 1536 blocks -> 6 blocks/CU.
// ---------------------------------------------------------------------------
__global__ __launch_bounds__(256) void gemm_qkv(const float* __restrict__ x,
                                                const float* __restrict__ Wq,
                                                const float* __restrict__ Wk,
                                                const float* __restrict__ Wv,
                                                u16* __restrict__ qb,
                                                u16* __restrict__ kb,
                                                u16* __restrict__ vb,
                                                const float* __restrict__ rot) {
    constexpr int Kd = 1024;
    constexpr int LDA = 40;                  // 32 + 8 pad
    __shared__ u16 As[64 * LDA];
    __shared__ u16 Bs[128 * LDA];

    const int tid = threadIdx.x;
    const int L   = tid & 63;
    const int w   = tid >> 6;
    const int m0  = blockIdx.y * 64;
    const int nG  = blockIdx.x * 128;        // [0, 3072)
    const int wsel = nG >> 10;
    const int wcol = nG & 1023;

    const float* W = (wsel == 0) ? Wq : (wsel == 1) ? Wk : Wv;
    u16* C         = (wsel == 0) ? qb : (wsel == 1) ? kb : vb;

    const int srow = tid >> 2;               // 0..63
    const int skc  = (tid & 3) * 8;
    const float* Ag = x + (size_t)(m0 + srow) * Kd + skc;
    const float* Wg = W + (size_t)(wcol + srow) * Kd + skc;
    u16* Asw = &As[srow * LDA + skc];
    u16* Bsw = &Bs[srow * LDA + skc];

    const int r16  = L & 15;
    const int quad = L >> 4;
    const int q8   = quad * 8;

    f32x4 acc[4][2];
#pragma unroll
    for (int i = 0; i < 4; i++)
#pragma unroll
        for (int j = 0; j < 2; j++) acc[i][j] = f32x4{0.f, 0.f, 0.f, 0.f};

    float4 aa0 = *(const float4*)(Ag);
    float4 ab0 = *(const float4*)(Ag + 4);
    float4 wa0 = *(const float4*)(Wg);
    float4 wb0 = *(const float4*)(Wg + 4);
    float4 wa1 = *(const float4*)(Wg + 64 * Kd);
    float4 wb1 = *(const float4*)(Wg + 64 * Kd + 4);

    const int cb = (w >> 1) * 64 + (w & 1) * 16;   // wave col base in tile

    for (int k0 = 0; k0 < Kd; k0 += 32) {
        __syncthreads();
        *(int4*)(Asw)            = pack8(aa0, ab0);
        *(int4*)(Bsw)            = pack8(wa0, wb0);
        *(int4*)(Bsw + 64 * LDA) = pack8(wa1, wb1);
        __syncthreads();

        if (k0 + 32 < Kd) {
            int kn = k0 + 32;
            aa0 = *(const float4*)(Ag + kn);
            ab0 = *(const float4*)(Ag + kn + 4);
            wa0 = *(const float4*)(Wg + kn);
            wb0 = *(const float4*)(Wg + kn + 4);
            wa1 = *(const float4*)(Wg + 64 * Kd + kn);
            wb1 = *(const float4*)(Wg + 64 * Kd + kn + 4);
        }

        bf16x8 af[4], bfr[2];
#pragma unroll
        for (int i = 0; i < 4; i++)
            af[i] = *(const bf16x8*)&As[(i * 16 + r16) * LDA + q8];
#pragma unroll
        for (int j = 0; j < 2; j++)
            bfr[j] = *(const bf16x8*)&Bs[(cb + j * 32 + r16) * LDA + q8];
#pragma unroll
        for (int mi = 0; mi < 4; mi++)
#pragma unroll
            for (int ni = 0; ni < 2; ni++)
                acc[mi][ni] = __builtin_amdgcn_mfma_f32_16x16x32_bf16(
                    af[mi], bfr[ni], acc[mi][ni], 0, 0, 0);
    }

    // epilogue: C/D layout row=quad*4+r, col=r16. d = (w&1)*16 + r16 (+32).
    const int dbase = (w & 1) * 16 + r16;
    if (wsel < 2) {
#pragma unroll
        for (int mi = 0; mi < 4; mi++)
#pragma unroll
            for (int r = 0; r < 4; r++) {
                int row = m0 + mi * 16 + quad * 4 + r;   // = b*T + t
                float s0, c0, s1, c1;
                __sincosf(rot[row * DHD + dbase], &s0, &c0);
                __sincosf(rot[row * DHD + dbase + 32], &s1, &c1);
                float x0 = acc[mi][0][r], x1 = acc[mi][1][r];
                C[(size_t)row * DIMD + wcol + cb + r16]      = f2bf(x0 * c0 - x1 * s0);
                C[(size_t)row * DIMD + wcol + cb + 32 + r16] = f2bf(x1 * c1 + x0 * s1);
            }
    } else {
#pragma unroll
        for (int mi = 0; mi < 4; mi++)
#pragma unroll
            for (int r = 0; r < 4; r++) {
                int row = m0 + mi * 16 + quad * 4 + r;
                C[(size_t)row * DIMD + wcol + cb + r16]      = f2bf(acc[mi][0][r]);
                C[(size_t)row * DIMD + wcol + cb + 32 + r16] = f2bf(acc[mi][1][r]);
            }
    }
}

// ---------------------------------------------------------------------------
// Output projection: C[m,n] = sum_k A[m,k]*W[n,k], A bf16 4096x1024,
// W f32 1024x1024, C f32. Tile 64x128, grid (8,64) = 512 blocks.
// ---------------------------------------------------------------------------
__global__ __launch_bounds__(256) void gemm_out(const u16* __restrict__ A,
                                                const float* __restrict__ W,
                                                float* __restrict__ C) {
    constexpr int Kd = 1024, Nd = 1024;
    constexpr int LDA = 40;
    __shared__ u16 As[64 * LDA];
    __shared__ u16 Bs[128 * LDA];

    const int tid = threadIdx.x;
    const int L   = tid & 63;
    const int w   = tid >> 6;
    const int m0  = blockIdx.y * 64;
    const int n0  = blockIdx.x * 128;

    const int srow = tid >> 2;
    const int skc  = (tid & 3) * 8;
    const u16*   Ag = A + (size_t)(m0 + srow) * Kd + skc;
    const float* Wg = W + (size_t)(n0 + srow) * Kd + skc;
    u16* Asw = &As[srow * LDA + skc];
    u16* Bsw = &Bs[srow * LDA + skc];

    const int r16  = L & 15;
    const int quad = L >> 4;
    const int q8   = quad * 8;

    f32x4 acc[4][2];
#pragma unroll
    for (int i = 0; i < 4; i++)
#pragma unroll
        for (int j = 0; j < 2; j++) acc[i][j] = f32x4{0.f, 0.f, 0.f, 0.f};

    int4   ah0 = *(const int4*)(Ag);
    float4 wa0 = *(const float4*)(Wg);
    float4 wb0 = *(const float4*)(Wg + 4);
    float4 wa1 = *(const float4*)(Wg + 64 * Kd);
    float4 wb1 = *(const float4*)(Wg + 64 * Kd + 4);

    const int cb = (w >> 1) * 64 + (w & 1) * 16;

    for (int k0 = 0; k0 < Kd; k0 += 32) {
        __syncthreads();
        *(int4*)(Asw)            = ah0;
        *(int4*)(Bsw)            = pack8(wa0, wb0);
        *(int4*)(Bsw + 64 * LDA) = pack8(wa1, wb1);
        __syncthreads();

        if (k0 + 32 < Kd) {
            int kn = k0 + 32;
            ah0 = *(const int4*)(Ag + kn);
            wa0 = *(const float4*)(Wg + kn);
            wb0 = *(const float4*)(Wg + kn + 4);
            wa1 = *(const float4*)(Wg + 64 * Kd + kn);
            wb1 = *(const float4*)(Wg + 64 * Kd + kn + 4);
        }

        bf16x8 af[4], bfr[2];
#pragma unroll
        for (int i = 0; i < 4; i++)
            af[i] = *(const bf16x8*)&As[(i * 16 + r16) * LDA + q8];
#pragma unroll
        for (int j = 0; j < 2; j++)
            bfr[j] = *(const bf16x8*)&Bs[(cb + j * 32 + r16) * LDA + q8];
#pragma unroll
        for (int mi = 0; mi < 4; mi++)
#pragma unroll
            for (int ni = 0; ni < 2; ni++)
                acc[mi][ni] = __builtin_amdgcn_mfma_f32_16x16x32_bf16(
                    af[mi], bfr[ni], acc[mi][ni], 0, 0, 0);
    }

#pragma unroll
    for (int mi = 0; mi < 4; mi++)
#pragma unroll
        for (int r = 0; r < 4; r++) {
            int row = m0 + mi * 16 + quad * 4 + r;
            C[(size_t)row * Nd + n0 + cb + r16]      = acc[mi][0][r];
            C[(size_t)row * Nd + n0 + cb + 32 + r16] = acc[mi][1][r];
        }
}

// ---------------------------------------------------------------------------
// Windowed causal attention: keys in [q-128, q]. Block = (b, h, 64 queries).
// ---------------------------------------------------------------------------
__global__ __launch_bounds__(256) void attn_kernel(const u16* __restrict__ Q,
                                                   const u16* __restrict__ K,
                                                   const u16* __restrict__ V,
                                                   u16* __restrict__ O) {
    constexpr int LDK = 72;    // 64 + 8 pad
    constexpr int LDV = 200;   // 192 + 8 pad
    __shared__ u16 Ks[192 * LDK];      // reused as P (4 waves x 16 x LDV)
    __shared__ u16 Qs[64 * LDK];
    __shared__ u16 VTs[64 * LDV];      // V transposed: [dh][key]

    const int tid = threadIdx.x;
    const int L   = tid & 63;
    const int w   = tid >> 6;
    const int b   = blockIdx.z;
    const int h   = blockIdx.y;
    const int q0  = blockIdx.x * 64;
    const int kstart = q0 - 128;

    for (int i = tid; i < 512; i += 256) {
        int qr = i >> 3, c = (i & 7) * 8;
        int t = q0 + qr;
        *(int4*)&Qs[qr * LDK + c] =
            *(const int4*)&Q[(size_t)(b * TT + t) * DIMD + h * DHD + c];
    }
    for (int i = tid; i < 1536; i += 256) {
        int kr = i >> 3, c = (i & 7) * 8;
        int kk = kstart + kr;
        int4 val = make_int4(0, 0, 0, 0);
        if (kk >= 0)
            val = *(const int4*)&K[(size_t)(b * TT + kk) * DIMD + h * DHD + c];
        *(int4*)&Ks[kr * LDK + c] = val;
    }
    for (int i = tid; i < 1536; i += 256) {
        int kr = i >> 3, c = (i & 7) * 8;
        int kk = kstart + kr;
        union { int4 v; u16 u[8]; } tmp;
        tmp.v = make_int4(0, 0, 0, 0);
        if (kk >= 0)
            tmp.v = *(const int4*)&V[(size_t)(b * TT + kk) * DIMD + h * DHD + c];
#pragma unroll
        for (int j = 0; j < 8; j++) VTs[(c + j) * LDV + kr] = tmp.u[j];
    }
    __syncthreads();

    const int r16  = L & 15;
    const int quad = L >> 4;
    const int q8   = quad * 8;

    bf16x8 aq0 = *(const bf16x8*)&Qs[(w * 16 + r16) * LDK + q8];
    bf16x8 aq1 = *(const bf16x8*)&Qs[(w * 16 + r16) * LDK + 32 + q8];

    float st[12][4];
    float rmax[4] = {-1e30f, -1e30f, -1e30f, -1e30f};
    const float SC = 0.125f;

#pragma unroll
    for (int kt = 0; kt < 12; kt++) {
        bf16x8 bk0 = *(const bf16x8*)&Ks[(kt * 16 + r16) * LDK + q8];
        bf16x8 bk1 = *(const bf16x8*)&Ks[(kt * 16 + r16) * LDK + 32 + q8];
        f32x4 s = f32x4{0.f, 0.f, 0.f, 0.f};
        s = __builtin_amdgcn_mfma_f32_16x16x32_bf16(aq0, bk0, s, 0, 0, 0);
        s = __builtin_amdgcn_mfma_f32_16x16x32_bf16(aq1, bk1, s, 0, 0, 0);
        int ka = kstart + kt * 16 + r16;
#pragma unroll
        for (int r = 0; r < 4; r++) {
            int qa = q0 + w * 16 + quad * 4 + r;
            float sv = s[r] * SC;
            bool ok = (ka >= 0) && (ka <= qa) && (ka >= qa - 128);
            sv = ok ? sv : -1e30f;
            st[kt][r] = sv;
            rmax[r] = fmaxf(rmax[r], sv);
        }
    }
#pragma unroll
    for (int off = 8; off >= 1; off >>= 1)
#pragma unroll
        for (int r = 0; r < 4; r++)
            rmax[r] = fmaxf(rmax[r], __shfl_xor(rmax[r], off, 64));

    __syncthreads();

    u16* Ps = &Ks[w * 16 * LDV];
    float rsum[4] = {0.f, 0.f, 0.f, 0.f};
#pragma unroll
    for (int kt = 0; kt < 12; kt++)
#pragma unroll
        for (int r = 0; r < 4; r++) {
            float p = __expf(st[kt][r] - rmax[r]);
            rsum[r] += p;
            Ps[(quad * 4 + r) * LDV + kt * 16 + r16] = f2bf(p);
        }
#pragma unroll
    for (int off = 8; off >= 1; off >>= 1)
#pragma unroll
        for (int r = 0; r < 4; r++)
            rsum[r] += __shfl_xor(rsum[r], off, 64);
    float rinv[4];
#pragma unroll
    for (int r = 0; r < 4; r++) rinv[r] = 1.0f / rsum[r];

    __syncthreads();

    bf16x8 pa[6];
#pragma unroll
    for (int kc = 0; kc < 6; kc++)
        pa[kc] = *(const bf16x8*)&Ps[r16 * LDV + kc * 32 + q8];

#pragma unroll
    for (int nt = 0; nt < 4; nt++) {
        f32x4 acc = f32x4{0.f, 0.f, 0.f, 0.f};
#pragma unroll
        for (int kc = 0; kc < 6; kc++) {
            bf16x8 bv = *(const bf16x8*)&VTs[(nt * 16 + r16) * LDV + kc * 32 + q8];
            acc = __builtin_amdgcn_mfma_f32_16x16x32_bf16(pa[kc], bv, acc, 0, 0, 0);
        }
#pragma unroll
        for (int r = 0; r < 4; r++) {
            int qa = q0 + w * 16 + quad * 4 + r;
            O[(size_t)(b * TT + qa) * DIMD + h * DHD + nt * 16 + r16] =
                f2bf(acc[r] * rinv[r]);
        }
    }
}

// ---------------------------------------------------------------------------
extern "C" void kernel_launch(void* const* d_in, const int* in_sizes, int n_in,
                              void* d_out, int out_size, void* d_ws, size_t ws_size,
                              hipStream_t stream) {
    const float* x   = (const float*)d_in[0];
    const float* rot = (const float*)d_in[2];
    const float* Wq  = (const float*)d_in[3];
    const float* Wk  = (const float*)d_in[4];
    const float* Wv  = (const float*)d_in[5];
    const float* Wo  = (const float*)d_in[6];
    float* out = (float*)d_out;

    u16* qb = (u16*)d_ws;
    u16* kb = qb + (size_t)MROWS * DIMD;
    u16* vb = kb + (size_t)MROWS * DIMD;
    u16* ab = vb + (size_t)MROWS * DIMD;

    gemm_qkv<<<dim3(3 * DIMD / 128, MROWS / 64), 256, 0, stream>>>(
        x, Wq, Wk, Wv, qb, kb, vb, rot);
    attn_kernel<<<dim3(TT / 64, NH, BB), 256, 0, stream>>>(qb, kb, vb, ab);
    gemm_out<<<dim3(DIMD / 128, MROWS / 64), 256, 0, stream>>>(ab, Wo, out);
}

// Round 4
// 185.361 us; speedup vs baseline: 1.3541x; 1.1323x over previous
//
#include <hip/hip_runtime.h>
#include <hip/hip_bf16.h>
#include <cstdint>

#define DIMD 1024
#define NH 16
#define DHD 64
#define BB 2
#define TT 2048
#define MROWS (BB * TT)   // 4096

typedef unsigned short u16;
typedef unsigned int u32;
typedef __attribute__((ext_vector_type(8))) __bf16 bf16x8;
typedef __attribute__((ext_vector_type(4))) float f32x4;

__device__ __forceinline__ float bf2f(u16 u) {
    union { unsigned int i; float f; } v; v.i = ((unsigned int)u) << 16; return v.f;
}
__device__ __forceinline__ u16 f2bf(float f) {
    union { float f; unsigned int i; } v; v.f = f;
    unsigned int u = v.i;
    unsigned int r = (u + 0x7fffu + ((u >> 16) & 1u)) >> 16;
    return (u16)r;
}
__device__ __forceinline__ int4 pack8(const float4& a, const float4& b) {
    union { int4 v; u16 u[8]; } t;
    t.u[0] = f2bf(a.x); t.u[1] = f2bf(a.y); t.u[2] = f2bf(a.z); t.u[3] = f2bf(a.w);
    t.u[4] = f2bf(b.x); t.u[5] = f2bf(b.y); t.u[6] = f2bf(b.z); t.u[7] = f2bf(b.w);
    return t.v;
}
// async global->LDS, 16B per lane. LDS dest = wave-uniform base + lane*16.
__device__ __forceinline__ void gl_lds16(const u16* g, u16* l) {
    __builtin_amdgcn_global_load_lds(
        (const __attribute__((address_space(1))) u32*)g,
        (__attribute__((address_space(3))) u32*)l, 16, 0, 0);
}

// ---------------------------------------------------------------------------
// One-shot f32 -> bf16 conversion of x, Wq|Wk|Wv (concat), Wo.
// 1,048,576 threads x 8 elements. Memory-bound.
// ---------------------------------------------------------------------------
__global__ __launch_bounds__(256) void convert_all(const float* __restrict__ x,
                                                   const float* __restrict__ Wq,
                                                   const float* __restrict__ Wk,
                                                   const float* __restrict__ Wv,
                                                   const float* __restrict__ Wo,
                                                   u16* __restrict__ xb,
                                                   u16* __restrict__ wqkv,
                                                   u16* __restrict__ wob) {
    int t = blockIdx.x * 256 + threadIdx.x;
    const float* src; u16* dst; int rel;
    if (t < 524288)      { src = x;  dst = xb;             rel = t; }
    else if (t < 655360) { src = Wq; dst = wqkv;           rel = t - 524288; }
    else if (t < 786432) { src = Wk; dst = wqkv + 1048576; rel = t - 655360; }
    else if (t < 917504) { src = Wv; dst = wqkv + 2097152; rel = t - 786432; }
    else                 { src = Wo; dst = wob;            rel = t - 917504; }
    size_t e = (size_t)rel * 8;
    float4 a = *(const float4*)(src + e);
    float4 b = *(const float4*)(src + e + 4);
    *(int4*)(dst + e) = pack8(a, b);
}

// ---------------------------------------------------------------------------
// Fused QKV projection + RoPE. C[m,n] = sum_k xb[m,k]*wqkv[n,k], N=3072.
// 128x128 tile, BK=32, global_load_lds staging into unpadded LDS.
// 4 waves (2x2), each 64x64 via 4x4 MFMA 16x16x32. Grid (24,32)=768 blocks.
// ---------------------------------------------------------------------------
__global__ __launch_bounds__(256) void gemm_qkv(const u16* __restrict__ xb,
                                                const u16* __restrict__ wqkv,
                                                u16* __restrict__ qb,
                                                u16* __restrict__ kb,
                                                u16* __restrict__ vb,
                                                const float* __restrict__ rot) {
    constexpr int Kd = 1024;
    __shared__ u16 As[128 * 32];
    __shared__ u16 Bs[128 * 32];

    const int tid  = threadIdx.x;
    const int lane = tid & 63;
    const int w    = tid >> 6;
    const int m0   = blockIdx.y * 128;
    const int n0   = blockIdx.x * 128;      // [0, 3072)

    // staging: wave w stages rows [32w, 32w+32) of A and B (2 instrs each)
    const u16* Ag = xb   + (size_t)(m0 + 32 * w + (lane >> 2)) * Kd + (lane & 3) * 8;
    const u16* Bg = wqkv + (size_t)(n0 + 32 * w + (lane & 63) / 4) * Kd + (lane & 3) * 8;
    u16* Al0 = &As[(32 * w) * 32];
    u16* Al1 = &As[(32 * w + 16) * 32];
    u16* Bl0 = &Bs[(32 * w) * 32];
    u16* Bl1 = &Bs[(32 * w + 16) * 32];

    const int r16  = lane & 15;
    const int quad = lane >> 4;
    const int q8   = quad * 8;
    const int wm   = (w >> 1) * 64;
    const int wn   = (w & 1) * 64;

    f32x4 acc[4][4];
#pragma unroll
    for (int i = 0; i < 4; i++)
#pragma unroll
        for (int j = 0; j < 4; j++) acc[i][j] = f32x4{0.f, 0.f, 0.f, 0.f};

    for (int k0 = 0; k0 < Kd; k0 += 32) {
        __syncthreads();
        gl_lds16(Ag + k0, Al0);
        gl_lds16(Ag + 16 * Kd + k0, Al1);
        gl_lds16(Bg + k0, Bl0);
        gl_lds16(Bg + 16 * Kd + k0, Bl1);
        __syncthreads();   // drains vmcnt(0): loads have landed

        bf16x8 af[4], bfr[4];
#pragma unroll
        for (int i = 0; i < 4; i++)
            af[i] = *(const bf16x8*)&As[(wm + i * 16 + r16) * 32 + q8];
#pragma unroll
        for (int j = 0; j < 4; j++)
            bfr[j] = *(const bf16x8*)&Bs[(wn + j * 16 + r16) * 32 + q8];
#pragma unroll
        for (int mi = 0; mi < 4; mi++)
#pragma unroll
            for (int ni = 0; ni < 4; ni++)
                acc[mi][ni] = __builtin_amdgcn_mfma_f32_16x16x32_bf16(
                    af[mi], bfr[ni], acc[mi][ni], 0, 0, 0);
    }

    // epilogue. col = n0 + wn + ni*16 + r16; within-head d = ni*16+r16 (ni<2),
    // pair (d, d+32) = (acc[mi][ni], acc[mi][ni+2]).
    const int wsel = n0 >> 10;
    const int nloc = (n0 & 1023) + wn;
    u16* C = (wsel == 0) ? qb : (wsel == 1) ? kb : vb;

    if (wsel < 2) {
#pragma unroll
        for (int mi = 0; mi < 4; mi++)
#pragma unroll
            for (int r = 0; r < 4; r++) {
                int row = m0 + wm + mi * 16 + quad * 4 + r;   // = b*T + t
#pragma unroll
                for (int ni = 0; ni < 2; ni++) {
                    int d = ni * 16 + r16;
                    float s0, c0, s1, c1;
                    __sincosf(rot[row * DHD + d], &s0, &c0);
                    __sincosf(rot[row * DHD + d + 32], &s1, &c1);
                    float x0 = acc[mi][ni][r], x1 = acc[mi][ni + 2][r];
                    C[(size_t)row * DIMD + nloc + d]      = f2bf(x0 * c0 - x1 * s0);
                    C[(size_t)row * DIMD + nloc + d + 32] = f2bf(x1 * c1 + x0 * s1);
                }
            }
    } else {
#pragma unroll
        for (int mi = 0; mi < 4; mi++)
#pragma unroll
            for (int ni = 0; ni < 4; ni++)
#pragma unroll
                for (int r = 0; r < 4; r++) {
                    int row = m0 + wm + mi * 16 + quad * 4 + r;
                    C[(size_t)row * DIMD + nloc + ni * 16 + r16] = f2bf(acc[mi][ni][r]);
                }
    }
}

// ---------------------------------------------------------------------------
// Output projection: C = A @ Wo^T, A bf16 4096x1024, Wo bf16, C f32.
// 64x128 tile, grid (8,64) = 512 blocks. Wave w: cols cb+{0,32}, acc[4][2].
// ---------------------------------------------------------------------------
__global__ __launch_bounds__(256) void gemm_out(const u16* __restrict__ A,
                                                const u16* __restrict__ Wb,
                                                float* __restrict__ C) {
    constexpr int Kd = 1024, Nd = 1024;
    __shared__ u16 As[64 * 32];
    __shared__ u16 Bs[128 * 32];

    const int tid  = threadIdx.x;
    const int lane = tid & 63;
    const int w    = tid >> 6;
    const int m0   = blockIdx.y * 64;
    const int n0   = blockIdx.x * 128;

    const u16* Ag = A  + (size_t)(m0 + 16 * w + (lane >> 2)) * Kd + (lane & 3) * 8;
    const u16* Bg = Wb + (size_t)(n0 + 32 * w + (lane >> 2)) * Kd + (lane & 3) * 8;
    u16* Al  = &As[(16 * w) * 32];
    u16* Bl0 = &Bs[(32 * w) * 32];
    u16* Bl1 = &Bs[(32 * w + 16) * 32];

    const int r16  = lane & 15;
    const int quad = lane >> 4;
    const int q8   = quad * 8;
    const int cb   = (w >> 1) * 64 + (w & 1) * 16;

    f32x4 acc[4][2];
#pragma unroll
    for (int i = 0; i < 4; i++)
#pragma unroll
        for (int j = 0; j < 2; j++) acc[i][j] = f32x4{0.f, 0.f, 0.f, 0.f};

    for (int k0 = 0; k0 < Kd; k0 += 32) {
        __syncthreads();
        gl_lds16(Ag + k0, Al);
        gl_lds16(Bg + k0, Bl0);
        gl_lds16(Bg + 16 * Kd + k0, Bl1);
        __syncthreads();

        bf16x8 af[4], bfr[2];
#pragma unroll
        for (int i = 0; i < 4; i++)
            af[i] = *(const bf16x8*)&As[(i * 16 + r16) * 32 + q8];
#pragma unroll
        for (int j = 0; j < 2; j++)
            bfr[j] = *(const bf16x8*)&Bs[(cb + j * 32 + r16) * 32 + q8];
#pragma unroll
        for (int mi = 0; mi < 4; mi++)
#pragma unroll
            for (int ni = 0; ni < 2; ni++)
                acc[mi][ni] = __builtin_amdgcn_mfma_f32_16x16x32_bf16(
                    af[mi], bfr[ni], acc[mi][ni], 0, 0, 0);
    }

#pragma unroll
    for (int mi = 0; mi < 4; mi++)
#pragma unroll
        for (int j = 0; j < 2; j++)
#pragma unroll
            for (int r = 0; r < 4; r++) {
                int row = m0 + mi * 16 + quad * 4 + r;
                C[(size_t)row * Nd + n0 + cb + j * 32 + r16] = acc[mi][j][r];
            }
}

// ---------------------------------------------------------------------------
// Windowed causal attention: keys in [q-128, q]. Block = (b, h, 64 queries).
// ---------------------------------------------------------------------------
__global__ __launch_bounds__(256) void attn_kernel(const u16* __restrict__ Q,
                                                   const u16* __restrict__ K,
                                                   const u16* __restrict__ V,
                                                   u16* __restrict__ O) {
    constexpr int LDK = 72;    // 64 + 8 pad
    constexpr int LDV = 200;   // 192 + 8 pad
    __shared__ u16 Ks[192 * LDK];      // reused as P (4 waves x 16 x LDV)
    __shared__ u16 Qs[64 * LDK];
    __shared__ u16 VTs[64 * LDV];      // V transposed: [dh][key]

    const int tid = threadIdx.x;
    const int L   = tid & 63;
    const int w   = tid >> 6;
    const int b   = blockIdx.z;
    const int h   = blockIdx.y;
    const int q0  = blockIdx.x * 64;
    const int kstart = q0 - 128;

    for (int i = tid; i < 512; i += 256) {
        int qr = i >> 3, c = (i & 7) * 8;
        int t = q0 + qr;
        *(int4*)&Qs[qr * LDK + c] =
            *(const int4*)&Q[(size_t)(b * TT + t) * DIMD + h * DHD + c];
    }
    for (int i = tid; i < 1536; i += 256) {
        int kr = i >> 3, c = (i & 7) * 8;
        int kk = kstart + kr;
        int4 val = make_int4(0, 0, 0, 0);
        if (kk >= 0)
            val = *(const int4*)&K[(size_t)(b * TT + kk) * DIMD + h * DHD + c];
        *(int4*)&Ks[kr * LDK + c] = val;
    }
    for (int i = tid; i < 1536; i += 256) {
        int kr = i >> 3, c = (i & 7) * 8;
        int kk = kstart + kr;
        union { int4 v; u16 u[8]; } tmp;
        tmp.v = make_int4(0, 0, 0, 0);
        if (kk >= 0)
            tmp.v = *(const int4*)&V[(size_t)(b * TT + kk) * DIMD + h * DHD + c];
#pragma unroll
        for (int j = 0; j < 8; j++) VTs[(c + j) * LDV + kr] = tmp.u[j];
    }
    __syncthreads();

    const int r16  = L & 15;
    const int quad = L >> 4;
    const int q8   = quad * 8;

    bf16x8 aq0 = *(const bf16x8*)&Qs[(w * 16 + r16) * LDK + q8];
    bf16x8 aq1 = *(const bf16x8*)&Qs[(w * 16 + r16) * LDK + 32 + q8];

    float st[12][4];
    float rmax[4] = {-1e30f, -1e30f, -1e30f, -1e30f};
    const float SC = 0.125f;

#pragma unroll
    for (int kt = 0; kt < 12; kt++) {
        bf16x8 bk0 = *(const bf16x8*)&Ks[(kt * 16 + r16) * LDK + q8];
        bf16x8 bk1 = *(const bf16x8*)&Ks[(kt * 16 + r16) * LDK + 32 + q8];
        f32x4 s = f32x4{0.f, 0.f, 0.f, 0.f};
        s = __builtin_amdgcn_mfma_f32_16x16x32_bf16(aq0, bk0, s, 0, 0, 0);
        s = __builtin_amdgcn_mfma_f32_16x16x32_bf16(aq1, bk1, s, 0, 0, 0);
        int ka = kstart + kt * 16 + r16;
#pragma unroll
        for (int r = 0; r < 4; r++) {
            int qa = q0 + w * 16 + quad * 4 + r;
            float sv = s[r] * SC;
            bool ok = (ka >= 0) && (ka <= qa) && (ka >= qa - 128);
            sv = ok ? sv : -1e30f;
            st[kt][r] = sv;
            rmax[r] = fmaxf(rmax[r], sv);
        }
    }
#pragma unroll
    for (int off = 8; off >= 1; off >>= 1)
#pragma unroll
        for (int r = 0; r < 4; r++)
            rmax[r] = fmaxf(rmax[r], __shfl_xor(rmax[r], off, 64));

    __syncthreads();

    u16* Ps = &Ks[w * 16 * LDV];
    float rsum[4] = {0.f, 0.f, 0.f, 0.f};
#pragma unroll
    for (int kt = 0; kt < 12; kt++)
#pragma unroll
        for (int r = 0; r < 4; r++) {
            float p = __expf(st[kt][r] - rmax[r]);
            rsum[r] += p;
            Ps[(quad * 4 + r) * LDV + kt * 16 + r16] = f2bf(p);
        }
#pragma unroll
    for (int off = 8; off >= 1; off >>= 1)
#pragma unroll
        for (int r = 0; r < 4; r++)
            rsum[r] += __shfl_xor(rsum[r], off, 64);
    float rinv[4];
#pragma unroll
    for (int r = 0; r < 4; r++) rinv[r] = 1.0f / rsum[r];

    __syncthreads();

    bf16x8 pa[6];
#pragma unroll
    for (int kc = 0; kc < 6; kc++)
        pa[kc] = *(const bf16x8*)&Ps[r16 * LDV + kc * 32 + q8];

#pragma unroll
    for (int nt = 0; nt < 4; nt++) {
        f32x4 acc = f32x4{0.f, 0.f, 0.f, 0.f};
#pragma unroll
        for (int kc = 0; kc < 6; kc++) {
            bf16x8 bv = *(const bf16x8*)&VTs[(nt * 16 + r16) * LDV + kc * 32 + q8];
            acc = __builtin_amdgcn_mfma_f32_16x16x32_bf16(pa[kc], bv, acc, 0, 0, 0);
        }
#pragma unroll
        for (int r = 0; r < 4; r++) {
            int qa = q0 + w * 16 + quad * 4 + r;
            O[(size_t)(b * TT + qa) * DIMD + h * DHD + nt * 16 + r16] =
                f2bf(acc[r] * rinv[r]);
        }
    }
}

// ---------------------------------------------------------------------------
extern "C" void kernel_launch(void* const* d_in, const int* in_sizes, int n_in,
                              void* d_out, int out_size, void* d_ws, size_t ws_size,
                              hipStream_t stream) {
    const float* x   = (const float*)d_in[0];
    const float* rot = (const float*)d_in[2];
    const float* Wq  = (const float*)d_in[3];
    const float* Wk  = (const float*)d_in[4];
    const float* Wv  = (const float*)d_in[5];
    const float* Wo  = (const float*)d_in[6];
    float* out = (float*)d_out;

    u16* xb   = (u16*)d_ws;               // 4M elems
    u16* wqkv = xb + 4194304;             // 3M (Wq|Wk|Wv)
    u16* wob  = wqkv + 3145728;           // 1M
    u16* qb   = wob + 1048576;            // 4M
    u16* kb   = qb + 4194304;             // 4M
    u16* vb   = kb + 4194304;             // 4M
    u16* ab   = vb + 4194304;             // 4M  (total 48 MB)

    convert_all<<<4096, 256, 0, stream>>>(x, Wq, Wk, Wv, Wo, xb, wqkv, wob);
    gemm_qkv<<<dim3(3 * DIMD / 128, MROWS / 128), 256, 0, stream>>>(
        xb, wqkv, qb, kb, vb, rot);
    attn_kernel<<<dim3(TT / 64, NH, BB), 256, 0, stream>>>(qb, kb, vb, ab);
    gemm_out<<<dim3(DIMD / 128, MROWS / 64), 256, 0, stream>>>(ab, wob, out);
}